// Round 6
// baseline (203.053 us; speedup 1.0000x reference)
//
#include <hip/hip_runtime.h>
#include <hip/hip_bf16.h>
#include <stdint.h>

// Problem constants (B=8192, H=1024, E=8, K=2)
#define B_TOK 8192
#define H_DIM 1024
#define E_NUM 8
#define NSLOT (2 * B_TOK)

typedef __attribute__((ext_vector_type(8))) short short8;   // 8 bf16 = 4 VGPRs (MFMA A/B frag)
typedef __attribute__((ext_vector_type(4))) float floatx4;  // MFMA C/D frag

__device__ __forceinline__ unsigned short f32_to_bf16_rne(float f) {
  union { float f; uint32_t u; } v; v.f = f;
  uint32_t u = v.u;
  uint32_t r = u + 0x7FFFu + ((u >> 16) & 1u);
  return (unsigned short)(r >> 16);
}

// ---------- fused prologue ----------
// [0,2048)   : transpose expert_w [e][k][n] fp32 -> wt [e][n][k] bf16
// [2048,2560): route: x -> xb bf16 + fp32 gate logits + top-2 softmax
// [2560,3072): zero out (32 MB) so GEMM epilogue can atomicAdd
__global__ __launch_bounds__(256) void prep_kernel(const float* __restrict__ x,
                                                   const float* __restrict__ gw,
                                                   const float* __restrict__ ew,
                                                   unsigned short* __restrict__ xb,
                                                   unsigned short* __restrict__ wt,
                                                   int2* __restrict__ re,
                                                   float2* __restrict__ rw,
                                                   float* __restrict__ out) {
  __shared__ float smem[E_NUM * 1028];  // 32.9 KB, reused by transpose/route halves
  int bid = blockIdx.x;
  int tid = threadIdx.x;
  if (bid < 2048) {
    // ---- transpose 64x64 tile ----
    float (*tile)[65] = (float(*)[65])smem;  // [n][k], +1 pad
    int e = bid >> 8;
    int n0 = ((bid >> 4) & 15) * 64, k0 = (bid & 15) * 64;
    const float* wb = ew + ((size_t)e * H_DIM + k0) * H_DIM + n0;
    unsigned short* wtb = wt + ((size_t)e * H_DIM + n0) * H_DIM + k0;
    int rr = tid >> 4, c4 = tid & 15;
#pragma unroll
    for (int j = 0; j < 4; ++j) {
      int r = rr + j * 16;  // k-row in tile
      float4 v = *(const float4*)(wb + (size_t)r * H_DIM + c4 * 4);
      tile[c4 * 4 + 0][r] = v.x;  // 2-way bank aliasing only -> free
      tile[c4 * 4 + 1][r] = v.y;
      tile[c4 * 4 + 2][r] = v.z;
      tile[c4 * 4 + 3][r] = v.w;
    }
    __syncthreads();
#pragma unroll
    for (int j = 0; j < 4; ++j) {
      int nr = rr + j * 16;  // n-row in tile
      float4 v = *(const float4*)&tile[nr][c4 * 4];
      ushort4 o;
      o.x = f32_to_bf16_rne(v.x); o.y = f32_to_bf16_rne(v.y);
      o.z = f32_to_bf16_rne(v.z); o.w = f32_to_bf16_rne(v.w);
      *(ushort4*)(wtb + (size_t)nr * H_DIM + c4 * 4) = o;
    }
  } else if (bid < 2560) {
    // ---- route ----
    int rb = bid - 2048;  // 0..511
    float (*gws)[1028] = (float(*)[1028])smem;
#pragma unroll
    for (int it = 0; it < 8; ++it) {
      int i4 = it * 256 + tid;
      float4 v = ((const float4*)gw)[i4];
      int h = i4 >> 1, e0 = (i4 & 1) * 4;
      gws[e0 + 0][h] = v.x;
      gws[e0 + 1][h] = v.y;
      gws[e0 + 2][h] = v.z;
      gws[e0 + 3][h] = v.w;
    }
    __syncthreads();
    int wid = tid >> 6, lane = tid & 63;
    int b0 = rb * 16 + wid * 4;
    const float4* xr0 = (const float4*)(x + (size_t)(b0 + 0) * H_DIM);
    const float4* xr1 = (const float4*)(x + (size_t)(b0 + 1) * H_DIM);
    const float4* xr2 = (const float4*)(x + (size_t)(b0 + 2) * H_DIM);
    const float4* xr3 = (const float4*)(x + (size_t)(b0 + 3) * H_DIM);
    const float4* xr[4] = {xr0, xr1, xr2, xr3};
    float acc[4][E_NUM];
#pragma unroll
    for (int t = 0; t < 4; ++t)
#pragma unroll
      for (int e = 0; e < E_NUM; e++) acc[t][e] = 0.f;
#pragma unroll
    for (int it = 0; it < 4; ++it) {
      int c4 = it * 64 + lane;
      int h = c4 * 4;
      float4 g[E_NUM];
#pragma unroll
      for (int e = 0; e < E_NUM; e++) g[e] = *(const float4*)&gws[e][h];  // hoisted across 4 tokens
#pragma unroll
      for (int t = 0; t < 4; ++t) {
        float4 v = xr[t][c4];
        ushort4 o;
        o.x = f32_to_bf16_rne(v.x); o.y = f32_to_bf16_rne(v.y);
        o.z = f32_to_bf16_rne(v.z); o.w = f32_to_bf16_rne(v.w);
        ((ushort4*)(xb + (size_t)(b0 + t) * H_DIM))[c4] = o;
#pragma unroll
        for (int e = 0; e < E_NUM; e++)
          acc[t][e] += v.x * g[e].x + v.y * g[e].y + v.z * g[e].z + v.w * g[e].w;
      }
    }
#pragma unroll
    for (int t = 0; t < 4; ++t) {
#pragma unroll
      for (int e = 0; e < E_NUM; e++) {
#pragma unroll
        for (int off = 32; off; off >>= 1) acc[t][e] += __shfl_xor(acc[t][e], off, 64);
      }
      if (lane == 0) {
        int b = b0 + t;
        int e0 = 0; float v0 = acc[t][0];
#pragma unroll
        for (int e = 1; e < E_NUM; e++) if (acc[t][e] > v0) { v0 = acc[t][e]; e0 = e; }
        int e1 = -1; float v1 = -1e30f;
#pragma unroll
        for (int e = 0; e < E_NUM; e++) if (e != e0 && acc[t][e] > v1) { v1 = acc[t][e]; e1 = e; }
        float s = expf(v1 - v0);
        float w0 = 1.0f / (1.0f + s);
        re[b] = make_int2(e0, e1);
        rw[b] = make_float2(w0, s * w0);
      }
    }
  } else {
    // ---- zero out: 512 blocks x 64 KB ----
    int zb = bid - 2560;
    float4* o = (float4*)(out + (size_t)zb * 16384);
    float4 z = make_float4(0.f, 0.f, 0.f, 0.f);
#pragma unroll
    for (int j = 0; j < 16; ++j) o[j * 256 + tid] = z;
  }
}

// ---------- deterministic compaction: 8 blocks, single __syncthreads; emits per-slot weight ----------
__global__ __launch_bounds__(1024) void compact_kernel(const int2* __restrict__ re,
                                                       const float2* __restrict__ rw,
                                                       int* __restrict__ slot_tok,
                                                       float* __restrict__ slot_w,
                                                       int* __restrict__ ebase,
                                                       int* __restrict__ ecnt) {
  __shared__ int wcnt[8][16];
  __shared__ int bless[16];
  int e = blockIdx.x;
  int tid = threadIdx.x, wid = tid >> 6, lane = tid & 63;
  int cless = 0;
  int flag[8];
  unsigned long long mm[8];
#pragma unroll
  for (int it = 0; it < 8; ++it) {
    int2 ee = re[it * 1024 + tid];
    cless += (ee.x < e) + (ee.y < e);
    bool f0 = (ee.x == e), f1 = (ee.y == e);
    flag[it] = f0 ? 1 : (f1 ? 2 : 0);
    mm[it] = __ballot(f0 || f1);
    if (lane == 0) wcnt[it][wid] = __popcll(mm[it]);
  }
#pragma unroll
  for (int off = 32; off; off >>= 1) cless += __shfl_xor(cless, off, 64);
  if (lane == 0) bless[wid] = cless;
  __syncthreads();
  int base = 0;
#pragma unroll
  for (int i = 0; i < 16; ++i) base += bless[i];
  int run = 0;
#pragma unroll
  for (int it = 0; it < 8; ++it) {
    int wbase = 0, total = 0;
#pragma unroll
    for (int i = 0; i < 16; ++i) { int v = wcnt[it][i]; if (i < wid) wbase += v; total += v; }
    if (flag[it]) {
      int pre = __popcll(mm[it] & ((1ull << lane) - 1ull));
      int s = base + run + wbase + pre;
      int t = it * 1024 + tid;
      slot_tok[s] = t;
      float2 w = rw[t];
      slot_w[s] = (flag[it] == 1) ? w.x : w.y;
    }
    run += total;
  }
  if (tid == 0) { ebase[e] = base; ecnt[e] = run; }
}

// ---------- grouped gather-GEMM, 128x128, BK=64, fused weighted atomic scatter ----------
__device__ __forceinline__ void async_ld16(const void* g, void* l) {
  __builtin_amdgcn_global_load_lds((const __attribute__((address_space(1))) void*)g,
                                   (__attribute__((address_space(3))) void*)l, 16, 0, 0);
}

__global__ __launch_bounds__(256, 3) void moe_gemm_kernel(
    const unsigned short* __restrict__ xb,   // bf16 [B][H]
    const unsigned short* __restrict__ wt,   // bf16 [E][n][k]
    const int* __restrict__ ebase,
    const int* __restrict__ ecnt,
    const int* __restrict__ slot_tok,
    const float* __restrict__ slot_w,
    float* __restrict__ out) {               // fp32 [B][H], zeroed by prep
  int e = blockIdx.z;
  int c = ecnt[e];
  int m_idx = ((blockIdx.y >> 3) << 3) + blockIdx.x;  // XCD swizzle: all n of an m-tile on one XCD
  int n_idx = blockIdx.y & 7;
  int m0 = m_idx * 128;
  if (m0 >= c) return;
  int base = ebase[e];
  int n0 = n_idx * 128;

  __shared__ __align__(16) unsigned short As[128 * 64];  // 16 KB, rows of 128 B (8 chunks)
  __shared__ __align__(16) unsigned short Bs[128 * 64];  // 16 KB

  int tid = threadIdx.x, wid = tid >> 6, lane = tid & 63;
  int rloc = lane >> 3;   // row within 8-row group
  int cl = lane & 7;      // 16B chunk slot in LDS row
  const int* st = slot_tok + base;
  const float* sw_ = slot_w + base;

  const unsigned short* gA[4];
  const unsigned short* gB[4];
  unsigned short* lA[4];
  unsigned short* lB[4];
#pragma unroll
  for (int j = 0; j < 4; ++j) {
    int rl = wid * 32 + j * 8 + rloc;          // tile row 0..127
    int g = (cl ^ (rl & 7)) * 8;               // swizzled global chunk -> LDS chunk cl
    int ra = min(m0 + rl, c - 1);
    gA[j] = xb + (size_t)st[ra] * H_DIM + g;
    gB[j] = wt + ((size_t)e * H_DIM + n0 + rl) * H_DIM + g;
    lA[j] = As + (wid * 32 + j * 8) * 64;      // wave-uniform base; lane lands at +lane*16B
    lB[j] = Bs + (wid * 32 + j * 8) * 64;
  }

  floatx4 acc[4][4];
#pragma unroll
  for (int a = 0; a < 4; ++a)
#pragma unroll
    for (int b = 0; b < 4; ++b)
#pragma unroll
      for (int q = 0; q < 4; ++q) acc[a][b][q] = 0.0f;

  int wm = (wid >> 1) * 64, wn = (wid & 1) * 64;
  int mr = lane & 15, kg = lane >> 4;
  int sw = mr & 7;  // reader swizzle

  for (int ks = 0; ks < 16; ++ks) {
    __syncthreads();
#pragma unroll
    for (int j = 0; j < 4; ++j) {
      async_ld16(gA[j], lA[j]);
      async_ld16(gB[j], lB[j]);
    }
#pragma unroll
    for (int j = 0; j < 4; ++j) { gA[j] += 64; gB[j] += 64; }
    __syncthreads();
#pragma unroll
    for (int kk = 0; kk < 2; ++kk) {
      int cb = ((kk * 4 + kg) ^ sw) * 8;
      short8 af[4], bfr[4];
#pragma unroll
      for (int t = 0; t < 4; ++t) {
        af[t]  = *(const short8*)(const void*)(As + (wm + t * 16 + mr) * 64 + cb);
        bfr[t] = *(const short8*)(const void*)(Bs + (wn + t * 16 + mr) * 64 + cb);
      }
#pragma unroll
      for (int tm = 0; tm < 4; ++tm)
#pragma unroll
        for (int tn = 0; tn < 4; ++tn)
          acc[tm][tn] = __builtin_amdgcn_mfma_f32_16x16x32_bf16(af[tm], bfr[tn], acc[tm][tn], 0, 0, 0);
    }
  }

  // epilogue: out[tok][n] += w * acc ; C/D layout col=lane&15, row=kg*4+q
#pragma unroll
  for (int tm = 0; tm < 4; ++tm) {
#pragma unroll
    for (int q = 0; q < 4; ++q) {
      int r = m0 + wm + tm * 16 + kg * 4 + q;
      if (r < c) {
        int tok = st[r];
        float w = sw_[r];
        float* orow = out + (size_t)tok * H_DIM + n0 + wn + mr;
#pragma unroll
        for (int tn = 0; tn < 4; ++tn) atomicAdd(orow + tn * 16, w * acc[tm][tn][q]);
      }
    }
  }
}

extern "C" void kernel_launch(void* const* d_in, const int* in_sizes, int n_in,
                              void* d_out, int out_size, void* d_ws, size_t ws_size,
                              hipStream_t stream) {
  const float* x  = (const float*)d_in[0];   // [8192][1024]
  const float* gw = (const float*)d_in[1];   // [1024][8]
  const float* ew = (const float*)d_in[2];   // [8][1024][1024]
  float* out = (float*)d_out;                // [8192][1024]

  char* ws = (char*)d_ws;
  unsigned short* xb = (unsigned short*)ws;                               // 16 MiB
  unsigned short* wt = (unsigned short*)(ws + (size_t)16 * 1024 * 1024);  // 16 MiB
  char* p = ws + (size_t)32 * 1024 * 1024;
  int2*   re       = (int2*)p;                      // 64 KiB
  float2* rw       = (float2*)(p + (64 << 10));     // 64 KiB
  int*    slot_tok = (int*)(p + (128 << 10));       // 64 KiB
  float*  slot_w   = (float*)(p + (192 << 10));     // 64 KiB
  int*    ebase    = (int*)(p + (256 << 10));
  int*    ecnt     = (int*)(p + (256 << 10) + 64);

  prep_kernel<<<3072, 256, 0, stream>>>(x, gw, ew, xb, wt, re, rw, out);
  compact_kernel<<<E_NUM, 1024, 0, stream>>>(re, rw, slot_tok, slot_w, ebase, ecnt);
  moe_gemm_kernel<<<dim3(8, 64, E_NUM), 256, 0, stream>>>(
      xb, wt, ebase, ecnt, slot_tok, slot_w, out);
}

// Round 8
// 174.598 us; speedup vs baseline: 1.1630x; 1.1630x over previous
//
#include <hip/hip_runtime.h>
#include <hip/hip_bf16.h>
#include <stdint.h>

// Problem constants (B=8192, H=1024, E=8, K=2)
#define B_TOK 8192
#define H_DIM 1024
#define E_NUM 8
#define NSLOT (2 * B_TOK)

typedef __attribute__((ext_vector_type(8))) short short8;   // 8 bf16 = 4 VGPRs (MFMA A/B frag)
typedef __attribute__((ext_vector_type(4))) float floatx4;  // MFMA C/D frag

__device__ __forceinline__ unsigned short f32_to_bf16_rne(float f) {
  union { float f; uint32_t u; } v; v.f = f;
  uint32_t u = v.u;
  uint32_t r = u + 0x7FFFu + ((u >> 16) & 1u);
  return (unsigned short)(r >> 16);
}
__device__ __forceinline__ float bf16_to_f32(unsigned short s) {
  union { uint32_t u; float f; } v; v.u = ((uint32_t)s) << 16;
  return v.f;
}

// ---------- fused prologue: [0,2048) transpose expert_w -> Wt bf16 ; [2048,2560) route ----------
__global__ __launch_bounds__(256) void prep_kernel(const float* __restrict__ x,
                                                   const float* __restrict__ gw,
                                                   const float* __restrict__ ew,
                                                   unsigned short* __restrict__ xb,
                                                   unsigned short* __restrict__ wt,
                                                   int2* __restrict__ re,
                                                   float2* __restrict__ rw) {
  __shared__ float smem[E_NUM * 1028];  // 32.9 KB, reused by both halves
  int bid = blockIdx.x;
  int tid = threadIdx.x;
  if (bid < 2048) {
    // ---- transpose 64x64 tile: w[e][k][n] fp32 -> wt[e][n][k] bf16 ----
    float (*tile)[65] = (float(*)[65])smem;  // [n][k], +1 pad
    int e = bid >> 8;
    int n0 = ((bid >> 4) & 15) * 64, k0 = (bid & 15) * 64;
    const float* wb = ew + ((size_t)e * H_DIM + k0) * H_DIM + n0;
    unsigned short* wtb = wt + ((size_t)e * H_DIM + n0) * H_DIM + k0;
    int rr = tid >> 4, c4 = tid & 15;
#pragma unroll
    for (int j = 0; j < 4; ++j) {
      int r = rr + j * 16;  // k-row in tile
      float4 v = *(const float4*)(wb + (size_t)r * H_DIM + c4 * 4);
      tile[c4 * 4 + 0][r] = v.x;  // 2-way bank aliasing only -> free
      tile[c4 * 4 + 1][r] = v.y;
      tile[c4 * 4 + 2][r] = v.z;
      tile[c4 * 4 + 3][r] = v.w;
    }
    __syncthreads();
#pragma unroll
    for (int j = 0; j < 4; ++j) {
      int nr = rr + j * 16;  // n-row in tile
      float4 v = *(const float4*)&tile[nr][c4 * 4];
      ushort4 o;
      o.x = f32_to_bf16_rne(v.x); o.y = f32_to_bf16_rne(v.y);
      o.z = f32_to_bf16_rne(v.z); o.w = f32_to_bf16_rne(v.w);
      *(ushort4*)(wtb + (size_t)nr * H_DIM + c4 * 4) = o;
    }
  } else {
    // ---- route: x fp32 -> xb bf16 + fp32 gate logits + top-2 softmax ----
    int rb = bid - 2048;  // 0..511
    float (*gws)[1028] = (float(*)[1028])smem;
#pragma unroll
    for (int it = 0; it < 8; ++it) {
      int i4 = it * 256 + tid;
      float4 v = ((const float4*)gw)[i4];
      int h = i4 >> 1, e0 = (i4 & 1) * 4;
      gws[e0 + 0][h] = v.x;
      gws[e0 + 1][h] = v.y;
      gws[e0 + 2][h] = v.z;
      gws[e0 + 3][h] = v.w;
    }
    __syncthreads();
    int wid = tid >> 6, lane = tid & 63;
    int b0 = rb * 16 + wid * 4;
    const float4* xr0 = (const float4*)(x + (size_t)(b0 + 0) * H_DIM);
    const float4* xr1 = (const float4*)(x + (size_t)(b0 + 1) * H_DIM);
    const float4* xr2 = (const float4*)(x + (size_t)(b0 + 2) * H_DIM);
    const float4* xr3 = (const float4*)(x + (size_t)(b0 + 3) * H_DIM);
    const float4* xr[4] = {xr0, xr1, xr2, xr3};
    float acc[4][E_NUM];
#pragma unroll
    for (int t = 0; t < 4; ++t)
#pragma unroll
      for (int e = 0; e < E_NUM; e++) acc[t][e] = 0.f;
#pragma unroll
    for (int it = 0; it < 4; ++it) {
      int c4 = it * 64 + lane;
      int h = c4 * 4;
      float4 g[E_NUM];
#pragma unroll
      for (int e = 0; e < E_NUM; e++) g[e] = *(const float4*)&gws[e][h];  // hoisted across 4 tokens
#pragma unroll
      for (int t = 0; t < 4; ++t) {
        float4 v = xr[t][c4];
        ushort4 o;
        o.x = f32_to_bf16_rne(v.x); o.y = f32_to_bf16_rne(v.y);
        o.z = f32_to_bf16_rne(v.z); o.w = f32_to_bf16_rne(v.w);
        ((ushort4*)(xb + (size_t)(b0 + t) * H_DIM))[c4] = o;
#pragma unroll
        for (int e = 0; e < E_NUM; e++)
          acc[t][e] += v.x * g[e].x + v.y * g[e].y + v.z * g[e].z + v.w * g[e].w;
      }
    }
#pragma unroll
    for (int t = 0; t < 4; ++t) {
#pragma unroll
      for (int e = 0; e < E_NUM; e++) {
#pragma unroll
        for (int off = 32; off; off >>= 1) acc[t][e] += __shfl_xor(acc[t][e], off, 64);
      }
      if (lane == 0) {
        int b = b0 + t;
        int e0 = 0; float v0 = acc[t][0];
#pragma unroll
        for (int e = 1; e < E_NUM; e++) if (acc[t][e] > v0) { v0 = acc[t][e]; e0 = e; }
        int e1 = -1; float v1 = -1e30f;
#pragma unroll
        for (int e = 0; e < E_NUM; e++) if (e != e0 && acc[t][e] > v1) { v1 = acc[t][e]; e1 = e; }
        float s = expf(v1 - v0);
        float w0 = 1.0f / (1.0f + s);
        re[b] = make_int2(e0, e1);
        rw[b] = make_float2(w0, s * w0);
      }
    }
  }
}

// ---------- deterministic compaction: 8 blocks, single __syncthreads ----------
__global__ __launch_bounds__(1024) void compact_kernel(const int2* __restrict__ re,
                                                       int* __restrict__ slot_tok,
                                                       int* __restrict__ yslot,
                                                       int* __restrict__ ebase,
                                                       int* __restrict__ ecnt) {
  __shared__ int wcnt[8][16];
  __shared__ int bless[16];
  int e = blockIdx.x;
  int tid = threadIdx.x, wid = tid >> 6, lane = tid & 63;
  int cless = 0;
  int flag[8];
  unsigned long long mm[8];
#pragma unroll
  for (int it = 0; it < 8; ++it) {
    int2 ee = re[it * 1024 + tid];
    cless += (ee.x < e) + (ee.y < e);
    bool f0 = (ee.x == e), f1 = (ee.y == e);
    flag[it] = f0 ? 1 : (f1 ? 2 : 0);
    mm[it] = __ballot(f0 || f1);
    if (lane == 0) wcnt[it][wid] = __popcll(mm[it]);
  }
#pragma unroll
  for (int off = 32; off; off >>= 1) cless += __shfl_xor(cless, off, 64);
  if (lane == 0) bless[wid] = cless;
  __syncthreads();
  int base = 0;
#pragma unroll
  for (int i = 0; i < 16; ++i) base += bless[i];
  int run = 0;
#pragma unroll
  for (int it = 0; it < 8; ++it) {
    int wbase = 0, total = 0;
#pragma unroll
    for (int i = 0; i < 16; ++i) { int v = wcnt[it][i]; if (i < wid) wbase += v; total += v; }
    if (flag[it]) {
      int pre = __popcll(mm[it] & ((1ull << lane) - 1ull));
      int s = base + run + wbase + pre;
      int t = it * 1024 + tid;
      slot_tok[s] = t;
      yslot[2 * t + (flag[it] == 1 ? 0 : 1)] = s;
    }
    run += total;
  }
  if (tid == 0) { ebase[e] = base; ecnt[e] = run; }
}

// ---------- grouped gather-GEMM, 128x128, BK=64, advancing 32-bit offsets, 4 blocks/CU ----------
__device__ __forceinline__ void async_ld16(const void* g, void* l) {
  __builtin_amdgcn_global_load_lds((const __attribute__((address_space(1))) void*)g,
                                   (__attribute__((address_space(3))) void*)l, 16, 0, 0);
}

__global__ __launch_bounds__(256, 4) void moe_gemm_kernel(
    const unsigned short* __restrict__ xb,   // bf16 [B][H]
    const unsigned short* __restrict__ wt,   // bf16 [E][n][k]
    const int* __restrict__ ebase,
    const int* __restrict__ ecnt,
    const int* __restrict__ slot_tok,
    unsigned short* __restrict__ y) {        // bf16 [NSLOT][H]
  int e = blockIdx.z;
  int c = ecnt[e];
  int m_idx = ((blockIdx.y >> 3) << 3) + blockIdx.x;  // XCD swizzle: all n of an m-tile on one XCD
  int n_idx = blockIdx.y & 7;
  int m0 = m_idx * 128;
  if (m0 >= c) return;
  int base = ebase[e];
  int n0 = n_idx * 128;

  __shared__ __align__(16) unsigned short As[128 * 64];  // 16 KB
  __shared__ __align__(16) unsigned short Bs[128 * 64];  // 16 KB

  int tid = threadIdx.x, lane = tid & 63;
  int widu = __builtin_amdgcn_readfirstlane(tid >> 6);  // wave-uniform -> SGPR
  int rloc = lane >> 3;   // row within 8-row group
  int cl = lane & 7;      // 16B chunk slot in LDS row
  const int* st = slot_tok + base;

  const char* xbB = (const char*)xb;   // uniform bases; 32-bit byte offsets advance
  const char* wtB = (const char*)wt;
  uint32_t oA[4], oB[4];
  unsigned short* lA[4];
  unsigned short* lB[4];
#pragma unroll
  for (int j = 0; j < 4; ++j) {
    int rl = widu * 32 + j * 8 + rloc;         // tile row 0..127
    int g = (cl ^ (rl & 7)) * 8;               // swizzled global chunk -> LDS chunk cl
    int ra = min(m0 + rl, c - 1);
    oA[j] = ((uint32_t)st[ra] * H_DIM + g) * 2;               // bytes, <=16.8M
    oB[j] = ((uint32_t)(e * H_DIM + n0 + rl) * H_DIM + g) * 2; // bytes, <=18.9M
    lA[j] = As + (widu * 32 + j * 8) * 64;     // wave-uniform base; lane lands at +lane*16B
    lB[j] = Bs + (widu * 32 + j * 8) * 64;
  }

  floatx4 acc[4][4];
#pragma unroll
  for (int a = 0; a < 4; ++a)
#pragma unroll
    for (int b = 0; b < 4; ++b)
#pragma unroll
      for (int q = 0; q < 4; ++q) acc[a][b][q] = 0.0f;

  int wm = (widu >> 1) * 64, wn = (widu & 1) * 64;
  int mr = lane & 15, kg = lane >> 4;
  int sw = mr & 7;  // reader swizzle

  for (int ks = 0; ks < 16; ++ks) {
    __syncthreads();
#pragma unroll
    for (int j = 0; j < 4; ++j) {
      async_ld16(xbB + oA[j], lA[j]);
      async_ld16(wtB + oB[j], lB[j]);
    }
#pragma unroll
    for (int j = 0; j < 4; ++j) { oA[j] += 128; oB[j] += 128; }
    __syncthreads();
#pragma unroll
    for (int kk = 0; kk < 2; ++kk) {
      int cb = ((kk * 4 + kg) ^ sw) * 8;
      short8 af[4];
#pragma unroll
      for (int t = 0; t < 4; ++t)
        af[t] = *(const short8*)(const void*)(As + (wm + t * 16 + mr) * 64 + cb);
      // interleave B-frag loads with MFMA columns: live frags = af[4] + 1
#pragma unroll
      for (int tn = 0; tn < 4; ++tn) {
        short8 bfr = *(const short8*)(const void*)(Bs + (wn + tn * 16 + mr) * 64 + cb);
#pragma unroll
        for (int tm = 0; tm < 4; ++tm)
          acc[tm][tn] = __builtin_amdgcn_mfma_f32_16x16x32_bf16(af[tm], bfr, acc[tm][tn], 0, 0, 0);
      }
    }
  }

  // epilogue: y[base+r][n] = bf16(acc); C/D layout col=lane&15, row=kg*4+q
#pragma unroll
  for (int tm = 0; tm < 4; ++tm) {
#pragma unroll
    for (int q = 0; q < 4; ++q) {
      int r = m0 + wm + tm * 16 + kg * 4 + q;
      if (r < c) {
        unsigned short* yrow = y + (size_t)(base + r) * H_DIM + n0 + wn + mr;
#pragma unroll
        for (int tn = 0; tn < 4; ++tn) yrow[tn * 16] = f32_to_bf16_rne(acc[tm][tn][q]);
      }
    }
  }
}

// ---------- combine: out[t] = w0*y[s0] + w1*y[s1]; 4 tokens/block, 4 f4/lane ----------
__global__ __launch_bounds__(256) void combine_kernel(const unsigned short* __restrict__ y,
                                                      const int* __restrict__ yslot,
                                                      const float2* __restrict__ rw,
                                                      float* __restrict__ out) {
  int wid = threadIdx.x >> 6, lane = threadIdx.x & 63;
  int t = blockIdx.x * 4 + wid;
  int s0 = yslot[2 * t], s1 = yslot[2 * t + 1];
  float2 w = rw[t];
  const ushort4* y0 = (const ushort4*)(y + (size_t)s0 * H_DIM);
  const ushort4* y1 = (const ushort4*)(y + (size_t)s1 * H_DIM);
  float4* o = (float4*)(out + (size_t)t * H_DIM);
  ushort4 a[4], b[4];
#pragma unroll
  for (int j = 0; j < 4; ++j) {
    int i = j * 64 + lane;
    a[j] = y0[i];
    b[j] = y1[i];
  }
#pragma unroll
  for (int j = 0; j < 4; ++j) {
    int i = j * 64 + lane;
    float4 r;
    r.x = w.x * bf16_to_f32(a[j].x) + w.y * bf16_to_f32(b[j].x);
    r.y = w.x * bf16_to_f32(a[j].y) + w.y * bf16_to_f32(b[j].y);
    r.z = w.x * bf16_to_f32(a[j].z) + w.y * bf16_to_f32(b[j].z);
    r.w = w.x * bf16_to_f32(a[j].w) + w.y * bf16_to_f32(b[j].w);
    o[i] = r;
  }
}

extern "C" void kernel_launch(void* const* d_in, const int* in_sizes, int n_in,
                              void* d_out, int out_size, void* d_ws, size_t ws_size,
                              hipStream_t stream) {
  const float* x  = (const float*)d_in[0];   // [8192][1024]
  const float* gw = (const float*)d_in[1];   // [1024][8]
  const float* ew = (const float*)d_in[2];   // [8][1024][1024]
  float* out = (float*)d_out;                // [8192][1024]

  char* ws = (char*)d_ws;
  unsigned short* xb = (unsigned short*)ws;                               // 16 MiB
  unsigned short* wt = (unsigned short*)(ws + (size_t)16 * 1024 * 1024);  // 16 MiB
  unsigned short* y  = (unsigned short*)(ws + (size_t)32 * 1024 * 1024);  // 32 MiB
  char* p = ws + (size_t)64 * 1024 * 1024;
  int2*   re       = (int2*)p;                      // 64 KiB
  float2* rw       = (float2*)(p + (64 << 10));     // 64 KiB
  int*    slot_tok = (int*)(p + (128 << 10));       // 64 KiB
  int*    yslot    = (int*)(p + (192 << 10));       // 64 KiB
  int*    ebase    = (int*)(p + (256 << 10));
  int*    ecnt     = (int*)(p + (256 << 10) + 64);

  prep_kernel<<<2560, 256, 0, stream>>>(x, gw, ew, xb, wt, re, rw);
  compact_kernel<<<E_NUM, 1024, 0, stream>>>(re, slot_tok, yslot, ebase, ecnt);
  moe_gemm_kernel<<<dim3(8, 64, E_NUM), 256, 0, stream>>>(
      xb, wt, ebase, ecnt, slot_tok, y);
  combine_kernel<<<B_TOK / 4, 256, 0, stream>>>(y, yslot, rw, out);
}